// Round 7
// baseline (1413.705 us; speedup 1.0000x reference)
//
#include <hip/hip_runtime.h>
#include <hip/hip_bf16.h>

typedef float f32x4 __attribute__((ext_vector_type(4)));
typedef float f32x2 __attribute__((ext_vector_type(2)));
typedef unsigned short u16x2 __attribute__((ext_vector_type(2)));
typedef unsigned short u16x4 __attribute__((ext_vector_type(4)));
typedef unsigned short u16x8 __attribute__((ext_vector_type(8)));
typedef short s16x8 __attribute__((ext_vector_type(8)));   // MFMA A/B fragment (8 bf16)

#define NN 200000
#define NE 400000
#define NG 4096
#define SCHUNK 1024
#define NSCAN ((NN + SCHUNK - 1) / SCHUNK)   // 196

template<int C> struct VecT;
template<> struct VecT<2> { using T = u16x2; };
template<> struct VecT<4> { using T = u16x4; };

__device__ __forceinline__ unsigned short f2bf(float f) {
    union { float f; unsigned int u; } v; v.f = f;
    unsigned int r = v.u + 0x7FFF + ((v.u >> 16) & 1);   // RNE
    return (unsigned short)(r >> 16);
}
__device__ __forceinline__ float bf2f(unsigned short b) {
    union { unsigned int u; float f; } v; v.u = ((unsigned int)b) << 16;
    return v.f;
}

// ---- int64-vs-int32 index detection ----
__global__ void detect_i64(const int* __restrict__ ei, int* __restrict__ flag) {
    unsigned long long m = __ballot(ei[threadIdx.x * 2 + 1] == 0);
    if (threadIdx.x == 0) *flag = (~m == 0ULL) ? 1 : 0;
}
__device__ __forceinline__ int load_idx(const int* p, long long i, int f64) {
    return f64 ? (int)((const long long*)p)[i] : p[i];
}

// ---------------- weight convert+transpose: Wt[n][k] = bf16(W[k][n]) ----------------
__global__ void wt_conv(const float* __restrict__ W, unsigned short* __restrict__ Wt,
                        int K, int N) {
    int tid = blockIdx.x * 256 + threadIdx.x;
    if (tid >= K * N) return;
    int n = tid / K, k = tid - n * K;
    Wt[tid] = f2bf(W[(size_t)k * N + n]);
}

__global__ __launch_bounds__(256) void copy_int(const int* __restrict__ a,
                                                int* __restrict__ b, int n) {
    int i = blockIdx.x * 256 + threadIdx.x;
    if (i < n) b[i] = a[i];
}

// ---------------- x (f32) -> xh (bf16), sequential ----------------
__global__ __launch_bounds__(256) void x2bf(const float* __restrict__ x,
                                            unsigned short* __restrict__ xh) {
    long long i = ((long long)blockIdx.x * 256 + threadIdx.x) * 4;
    if (i >= (long long)NN * 128) return;
    f32x4 v = *(const f32x4*)(x + i);
    u16x4 o; o.x = f2bf(v.x); o.y = f2bf(v.y); o.z = f2bf(v.z); o.w = f2bf(v.w);
    *(u16x4*)(xh + i) = o;
}

// ---------------- permute edge_attr into CSR order (once, reused 2x) ----------------
__global__ __launch_bounds__(256) void ea_perm(const float* __restrict__ ea,
                                               const int* __restrict__ eidx,
                                               const int* __restrict__ totE_p,
                                               float* __restrict__ eac) {
    int j = blockIdx.x * 256 + threadIdx.x;
    if (j >= *totE_p) return;
    int e = eidx[j];
    if ((unsigned)e >= NE) e = 0;
    const float* s = ea + (size_t)e * 16;
    float* d = eac + (size_t)j * 16;
#pragma unroll
    for (int k = 0; k < 4; ++k)
        *(f32x4*)(d + k * 4) = *(const f32x4*)(s + k * 4);
}

// ---------------- CSR build: histogram -> scan -> fill ----------------
__global__ __launch_bounds__(256) void hist_dst(const int* __restrict__ ei,
                                                const int* __restrict__ flag,
                                                int* __restrict__ deg) {
    int e = blockIdx.x * 256 + threadIdx.x;
    if (e >= NE) return;
    int f64 = *flag;
    int s = load_idx(ei, e, f64);
    int d = load_idx(ei, (long long)NE + e, f64);
    if ((unsigned)s < NN && (unsigned)d < NN) atomicAdd(&deg[d], 1);
}

__global__ __launch_bounds__(256) void scan_bsum(const int* __restrict__ deg,
                                                 int* __restrict__ bsum) {
    __shared__ int red[256];
    int t = threadIdx.x, base = blockIdx.x * SCHUNK + t * 4;
    int s = 0;
#pragma unroll
    for (int c = 0; c < 4; ++c) { int i = base + c; if (i < NN) s += deg[i]; }
    red[t] = s; __syncthreads();
    for (int o = 128; o > 0; o >>= 1) { if (t < o) red[t] += red[t + o]; __syncthreads(); }
    if (t == 0) bsum[blockIdx.x] = red[0];
}

__global__ void scan_carry(int* __restrict__ bsum, int* __restrict__ rowptr_end) {
    if (threadIdx.x == 0) {
        int run = 0;
        for (int i = 0; i < NSCAN; ++i) { int v = bsum[i]; bsum[i] = run; run += v; }
        *rowptr_end = run;   // rowptr[NN] = totE
    }
}

__global__ __launch_bounds__(256) void scan_final(const int* __restrict__ deg,
                                                  const int* __restrict__ bsum,
                                                  int* __restrict__ rowptr) {
    __shared__ int lds[256];
    int t = threadIdx.x, base = blockIdx.x * SCHUNK + t * 4;
    int v[4], s = 0;
#pragma unroll
    for (int c = 0; c < 4; ++c) { int i = base + c; v[c] = (i < NN) ? deg[i] : 0; s += v[c]; }
    lds[t] = s; __syncthreads();
    for (int o = 1; o < 256; o <<= 1) {
        int x = 0;
        if (t >= o) x = lds[t - o];
        __syncthreads();
        if (t >= o) lds[t] += x;
        __syncthreads();
    }
    int run = lds[t] - s + bsum[blockIdx.x];
#pragma unroll
    for (int c = 0; c < 4; ++c) { int i = base + c; if (i < NN) rowptr[i] = run; run += v[c]; }
}

__global__ __launch_bounds__(256) void fill_csr(const int* __restrict__ ei,
                                                const int* __restrict__ flag,
                                                int* __restrict__ cursor,
                                                int* __restrict__ srcs,
                                                int* __restrict__ eidx) {
    int e = blockIdx.x * 256 + threadIdx.x;
    if (e >= NE) return;
    int f64 = *flag;
    int s = load_idx(ei, e, f64);
    int d = load_idx(ei, (long long)NE + e, f64);
    if ((unsigned)s >= NN || (unsigned)d >= NN) return;
    int pos = atomicAdd(&cursor[d], 1);
    if ((unsigned)pos < NE) { srcs[pos] = s; eidx[pos] = e; }
}

// ---------------- stage 1: edge-parallel message build (packed f32x2 MLP) ----------------
// M[j] (64*C bf16) = bf16( relu( xh[srcs[j]] + eac[j] @ We + be ) )
template<int C>
__global__ __launch_bounds__(256)
void msg_build(const unsigned short* __restrict__ xh,
               const float* __restrict__ eac,
               const float* __restrict__ We, const float* __restrict__ be,
               const int* __restrict__ srcs, const int* __restrict__ totE_p,
               unsigned short* __restrict__ M) {
    using XV = typename VecT<C>::T;
    constexpr int D = 64 * C;
    constexpr int C2 = C / 2;
    const int wid  = (blockIdx.x * 256 + threadIdx.x) >> 6;
    const int lane = threadIdx.x & 63;
    const int totE = *totE_p;
    const int col = lane * C;

    f32x2 w2[16][C2], bb2[C2];
#pragma unroll
    for (int k = 0; k < 16; ++k)
#pragma unroll
        for (int c = 0; c < C2; ++c)
            w2[k][c] = *(const f32x2*)(We + k * D + col + 2 * c);
#pragma unroll
    for (int c = 0; c < C2; ++c) bb2[c] = *(const f32x2*)(be + col + 2 * c);

    const int j0 = wid * 4;
    int sv[4];
    XV xv[4];
#pragma unroll
    for (int u = 0; u < 4; ++u) {
        int j = j0 + u;
        sv[u] = (j < totE) ? srcs[j] : -1;
    }
#pragma unroll
    for (int u = 0; u < 4; ++u) {
        if ((unsigned)sv[u] < NN)
            xv[u] = *(const XV*)(xh + (size_t)sv[u] * D + col);
        else
            xv[u] = (XV)0;
    }
#pragma unroll
    for (int u = 0; u < 4; ++u) {
        int j = j0 + u;
        if (j >= totE) continue;
        const float* eap = eac + (size_t)j * 16;
        f32x4 e0 = *(const f32x4*)eap;
        f32x4 e1 = *(const f32x4*)(eap + 4);
        f32x4 e2 = *(const f32x4*)(eap + 8);
        f32x4 e3 = *(const f32x4*)(eap + 12);
        f32x2 m2[C2];
#pragma unroll
        for (int c = 0; c < C2; ++c) {
            f32x2 xx; xx.x = bf2f(xv[u][2 * c]); xx.y = bf2f(xv[u][2 * c + 1]);
            m2[c] = bb2[c] + xx;
        }
#pragma unroll
        for (int k = 0; k < 4; ++k) {
            f32x2 k0; k0.x = e0[k]; k0.y = e0[k];
            f32x2 k1; k1.x = e1[k]; k1.y = e1[k];
            f32x2 k2; k2.x = e2[k]; k2.y = e2[k];
            f32x2 k3; k3.x = e3[k]; k3.y = e3[k];
#pragma unroll
            for (int c = 0; c < C2; ++c) {
                m2[c] += k0 * w2[k][c];
                m2[c] += k1 * w2[4 + k][c];
                m2[c] += k2 * w2[8 + k][c];
                m2[c] += k3 * w2[12 + k][c];
            }
        }
        XV o;
#pragma unroll
        for (int c = 0; c < C2; ++c) {
            o[2 * c]     = f2bf(fmaxf(m2[c].x, 0.f));
            o[2 * c + 1] = f2bf(fmaxf(m2[c].y, 0.f));
        }
        *(XV*)(M + (size_t)j * D + col) = o;
    }
}

// ---------------- stage 2: segment-sum (sequential M reads; may run in-place) ----------------
template<int C>
__global__ __launch_bounds__(256)
void seg_sum(const unsigned short* __restrict__ M, const int* __restrict__ rowptr,
             const unsigned short* __restrict__ self, unsigned short* __restrict__ outp) {
    using XV = typename VecT<C>::T;
    constexpr int D = 64 * C;
    const int node = (blockIdx.x * 256 + threadIdx.x) >> 6;
    const int lane = threadIdx.x & 63;
    if (node >= NN) return;
    const int col = lane * C;
    int lo = rowptr[node], hi = rowptr[node + 1];
    if (lo > hi || (unsigned)hi > NE) { lo = 0; hi = 0; }

    float a[C];
    XV sv = *(const XV*)(self + (size_t)node * D + col);
#pragma unroll
    for (int c = 0; c < C; ++c) a[c] = bf2f(sv[c]);

    int j = lo;
    for (; j + 1 < hi; j += 2) {
        XV m0 = *(const XV*)(M + (size_t)j * D + col);
        XV m1 = *(const XV*)(M + (size_t)(j + 1) * D + col);
#pragma unroll
        for (int c = 0; c < C; ++c) a[c] += bf2f(m0[c]) + bf2f(m1[c]);
    }
    if (j < hi) {
        XV m0 = *(const XV*)(M + (size_t)j * D + col);
#pragma unroll
        for (int c = 0; c < C; ++c) a[c] += bf2f(m0[c]);
    }
    XV o;
#pragma unroll
    for (int c = 0; c < C; ++c) o[c] = f2bf(a[c]);
    *(XV*)(outp + (size_t)node * D + col) = o;
}

// ------- bf16 MFMA GEMM v3: full-K LDS A-tile, ONE barrier, B direct from L2 -------
// C[M,256] = relu(A @ W + bias); A bf16 [M,K], Wt bf16 [n][k] (128 KB, L2-resident).
// LDS pad +8 bf16/row -> row stride 68/132 dwords -> 16-row frag reads are 2-way
// bank-aliased = free (m136). B-frags prefetched distance-1 from global.
template<int K, typename CT>
__global__ __launch_bounds__(256)
void gemm_bias_relu(const unsigned short* __restrict__ A,
                    const unsigned short* __restrict__ Wt, const float* __restrict__ bias,
                    CT* __restrict__ C) {
    constexpr int LDT = K + 8;
    __shared__ unsigned short As[64 * LDT];
    const int n0 = blockIdx.x * 64;
    const int m0 = blockIdx.y * 64;
    const int tid = threadIdx.x;
    const int wave = tid >> 6;
    const int lane = tid & 63;
    const int lm = lane & 15;
    const int lq = lane >> 4;

    // ---- stage full A-tile once: 4 threads/row, interleaved 16B chunks ----
    {
        const int r = tid >> 2;
        const int c0 = (tid & 3) * 8;
        const unsigned short* src = A + (size_t)(m0 + r) * K + c0;
        unsigned short* dst = As + r * LDT + c0;
#pragma unroll
        for (int i = 0; i < K / 32; ++i)
            *(u16x8*)(dst + i * 32) = *(const u16x8*)(src + i * 32);
    }

    // ---- B fragments direct from global (same addrs across all m-blocks -> L2) ----
    const unsigned short* bp[4];
#pragma unroll
    for (int t = 0; t < 4; ++t)
        bp[t] = Wt + (size_t)(n0 + t * 16 + lm) * K + lq * 8;

    s16x8 bf[4], bfn[4];
#pragma unroll
    for (int t = 0; t < 4; ++t) bf[t] = *(const s16x8*)(bp[t]);

    __syncthreads();   // the only barrier

    f32x4 acc[4] = {};
    constexpr int NS = K / 32;
#pragma unroll
    for (int ks = 0; ks < NS; ++ks) {
        if (ks + 1 < NS) {
#pragma unroll
            for (int t = 0; t < 4; ++t)
                bfn[t] = *(const s16x8*)(bp[t] + (ks + 1) * 32);
        }
        s16x8 a = *(const s16x8*)(As + (wave * 16 + lm) * LDT + ks * 32 + lq * 8);
#pragma unroll
        for (int t = 0; t < 4; ++t)
            acc[t] = __builtin_amdgcn_mfma_f32_16x16x32_bf16(a, bf[t], acc[t], 0, 0, 0);
#pragma unroll
        for (int t = 0; t < 4; ++t) bf[t] = bfn[t];
    }

    // epilogue: C/D layout col=lane&15, row=(lane>>4)*4+reg
    const int row = m0 + wave * 16 + lq * 4;
#pragma unroll
    for (int t = 0; t < 4; ++t) {
        int col = n0 + t * 16 + lm;
        float bv = bias[col];
#pragma unroll
        for (int r = 0; r < 4; ++r) {
            float v = fmaxf(acc[t][r] + bv, 0.f);
            if constexpr (sizeof(CT) == 2)
                C[(size_t)(row + r) * 256 + col] = (CT)f2bf(v);
            else
                C[(size_t)(row + r) * 256 + col] = (CT)v;
        }
    }
}

// ------- mean pool -------
__global__ __launch_bounds__(256)
void pool_mean(const float* __restrict__ h, const int* __restrict__ batch,
               const int* __restrict__ flag, float* __restrict__ out) {
    const int f64 = *flag;
    int g = blockIdx.x;
    int a = 0, b = NN;
    while (a < b) { int m = (a + b) >> 1; if (load_idx(batch, m, f64) < g) a = m + 1; else b = m; }
    int lo = a;
    b = NN;
    while (a < b) { int m = (a + b) >> 1; if (load_idx(batch, m, f64) < g + 1) a = m + 1; else b = m; }
    int hi = a;
    int f = threadIdx.x;
    float s = 0.f;
    for (int n = lo; n < hi; ++n) s += h[(size_t)n * 256 + f];
    float cnt = (float)(hi - lo);
    out[(size_t)g * 256 + f] = s / fmaxf(cnt, 1.f);
}

extern "C" void kernel_launch(void* const* d_in, const int* in_sizes, int n_in,
                              void* d_out, int out_size, void* d_ws, size_t ws_size,
                              hipStream_t stream) {
    const float* x   = (const float*)d_in[0];
    const float* ea  = (const float*)d_in[1];
    const float* We1 = (const float*)d_in[2];
    const float* be1 = (const float*)d_in[3];
    const float* W1a = (const float*)d_in[4];
    const float* b1a = (const float*)d_in[5];
    const float* W1b = (const float*)d_in[6];
    const float* b1b = (const float*)d_in[7];
    const float* We2 = (const float*)d_in[8];
    const float* be2 = (const float*)d_in[9];
    const float* W2a = (const float*)d_in[10];
    const float* b2a = (const float*)d_in[11];
    const float* W2b = (const float*)d_in[12];
    const float* b2b = (const float*)d_in[13];
    const int*   ei  = (const int*)d_in[14];
    const int*   bat = (const int*)d_in[15];
    float* out = (float*)d_out;

    // ---- workspace: EXACT round-2-proven footprint (410,058,756 B) ----
    char* ws = (char*)d_ws;
    const size_t SZH = (size_t)NN * 256 * 2;   // 102,400,000
    unsigned short* A  = (unsigned short*)ws;
    unsigned short* B  = (unsigned short*)(ws + SZH);
    unsigned short* Cr = (unsigned short*)(ws + 2 * SZH);
    char* Dr = ws + 3 * SZH;
    char* q = Dr;
    int* deg    = (int*)q; q += (size_t)NN * 4;
    int* rowptr = (int*)q; q += (size_t)(NN + 1) * 4;
    int* cursor = (int*)q; q += (size_t)NN * 4;
    int* srcs   = (int*)q; q += (size_t)NE * 4;
    int* eidx   = (int*)q; q += (size_t)NE * 4;
    int* bsum   = (int*)q; q += (size_t)NSCAN * 4;
    q = Dr + ((q - Dr + 63) & ~63ll);
    float*          eac = (float*)q; q += (size_t)NE * 16 * 4;   // 25.6 MB
    unsigned short* xh  = (unsigned short*)q;                    // 51.2 MB
    char* p = ws + 4 * SZH;
    unsigned short* Wt1a = (unsigned short*)p; p += 128 * 256 * 2;
    unsigned short* Wt1b = (unsigned short*)p; p += 256 * 256 * 2;
    unsigned short* Wt2a = (unsigned short*)p; p += 256 * 256 * 2;
    unsigned short* Wt2b = (unsigned short*)p; p += 256 * 256 * 2;
    int* flag = (int*)p;

    detect_i64<<<1, 64, 0, stream>>>(ei, flag);
    wt_conv<<<(128 * 256 + 255) / 256, 256, 0, stream>>>(W1a, Wt1a, 128, 256);
    wt_conv<<<(256 * 256 + 255) / 256, 256, 0, stream>>>(W1b, Wt1b, 256, 256);
    wt_conv<<<(256 * 256 + 255) / 256, 256, 0, stream>>>(W2a, Wt2a, 256, 256);
    wt_conv<<<(256 * 256 + 255) / 256, 256, 0, stream>>>(W2b, Wt2b, 256, 256);

    // ---- CSR build (once; shared by both layers) ----
    hipMemsetAsync(deg, 0, (size_t)NN * 4, stream);
    hist_dst<<<(NE + 255) / 256, 256, 0, stream>>>(ei, flag, deg);
    scan_bsum<<<NSCAN, 256, 0, stream>>>(deg, bsum);
    scan_carry<<<1, 64, 0, stream>>>(bsum, rowptr + NN);
    scan_final<<<NSCAN, 256, 0, stream>>>(deg, bsum, rowptr);
    copy_int<<<(NN + 255) / 256, 256, 0, stream>>>(rowptr, cursor, NN);
    fill_csr<<<(NE + 255) / 256, 256, 0, stream>>>(ei, flag, cursor, srcs, eidx);
    ea_perm<<<(NE + 255) / 256, 256, 0, stream>>>(ea, eidx, rowptr + NN, eac);
    x2bf<<<(NN * 128 / 4 + 255) / 256, 256, 0, stream>>>(x, xh);

    const int GM_BLK = NE / 16;   // 25000: 4 waves x 4 slots per block
    const int GS_BLK = NN / 4;    // 50000: wave per node
    dim3 gg(4, 3125);             // GEMM grid (n, m)

    // ---- layer 1 (D=128) ----
    msg_build<2><<<GM_BLK, 256, 0, stream>>>(xh, eac, We1, be1, srcs, rowptr + NN, A);   // M1 -> A
    seg_sum<2><<<GS_BLK, 256, 0, stream>>>(A, rowptr, xh, B);                            // hin1 -> B
    gemm_bias_relu<128, unsigned short><<<gg, 256, 0, stream>>>(B, Wt1a, b1a, Cr);       // h1 -> C
    gemm_bias_relu<256, unsigned short><<<gg, 256, 0, stream>>>(Cr, Wt1b, b1b, A);       // h1o -> A

    // ---- layer 2 (D=256, single full-width pass) ----
    msg_build<4><<<GM_BLK, 256, 0, stream>>>(A, eac, We2, be2, srcs, rowptr + NN, B);    // M2 -> B∪C
    seg_sum<4><<<GS_BLK, 256, 0, stream>>>(B, rowptr, A, A);                             // hin2 in-place A
    gemm_bias_relu<256, unsigned short><<<gg, 256, 0, stream>>>(A, Wt2a, b2a, B);        // h2a -> B
    gemm_bias_relu<256, float><<<gg, 256, 0, stream>>>(B, Wt2b, b2b, (float*)Cr);        // h2b f32 -> C∪D

    // ---- mean pool ----
    pool_mean<<<NG, 256, 0, stream>>>((const float*)Cr, bat, flag, out);
}

// Round 8
// 1034.651 us; speedup vs baseline: 1.3664x; 1.3664x over previous
//
#include <hip/hip_runtime.h>
#include <hip/hip_bf16.h>

typedef float f32x4 __attribute__((ext_vector_type(4)));
typedef float f32x2 __attribute__((ext_vector_type(2)));
typedef unsigned short u16x2 __attribute__((ext_vector_type(2)));
typedef unsigned short u16x4 __attribute__((ext_vector_type(4)));
typedef unsigned short u16x8 __attribute__((ext_vector_type(8)));
typedef short s16x8 __attribute__((ext_vector_type(8)));   // MFMA A/B fragment (8 bf16)

#define NN 200000
#define NE 400000
#define NG 4096
#define SCHUNK 1024
#define NSCAN ((NN + SCHUNK - 1) / SCHUNK)   // 196

template<int C> struct VecT;
template<> struct VecT<2> { using T = u16x2; };
template<> struct VecT<4> { using T = u16x4; };

__device__ __forceinline__ unsigned short f2bf(float f) {
    union { float f; unsigned int u; } v; v.f = f;
    unsigned int r = v.u + 0x7FFF + ((v.u >> 16) & 1);   // RNE
    return (unsigned short)(r >> 16);
}
__device__ __forceinline__ float bf2f(unsigned short b) {
    union { unsigned int u; float f; } v; v.u = ((unsigned int)b) << 16;
    return v.f;
}

// ---- int64-vs-int32 index detection ----
__global__ void detect_i64(const int* __restrict__ ei, int* __restrict__ flag) {
    unsigned long long m = __ballot(ei[threadIdx.x * 2 + 1] == 0);
    if (threadIdx.x == 0) *flag = (~m == 0ULL) ? 1 : 0;
}
__device__ __forceinline__ int load_idx(const int* p, long long i, int f64) {
    return f64 ? (int)((const long long*)p)[i] : p[i];
}

// ---------------- weight convert+transpose: Wt[n][k] = bf16(W[k][n]) ----------------
__global__ void wt_conv(const float* __restrict__ W, unsigned short* __restrict__ Wt,
                        int K, int N) {
    int tid = blockIdx.x * 256 + threadIdx.x;
    if (tid >= K * N) return;
    int n = tid / K, k = tid - n * K;
    Wt[tid] = f2bf(W[(size_t)k * N + n]);
}

__global__ __launch_bounds__(256) void copy_int(const int* __restrict__ a,
                                                int* __restrict__ b, int n) {
    int i = blockIdx.x * 256 + threadIdx.x;
    if (i < n) b[i] = a[i];
}

// ---------------- x (f32) -> xh (bf16), sequential ----------------
__global__ __launch_bounds__(256) void x2bf(const float* __restrict__ x,
                                            unsigned short* __restrict__ xh) {
    long long i = ((long long)blockIdx.x * 256 + threadIdx.x) * 4;
    if (i >= (long long)NN * 128) return;
    f32x4 v = *(const f32x4*)(x + i);
    u16x4 o; o.x = f2bf(v.x); o.y = f2bf(v.y); o.z = f2bf(v.z); o.w = f2bf(v.w);
    *(u16x4*)(xh + i) = o;
}

// ---------------- permute edge_attr into CSR order (once, reused 2x) ----------------
__global__ __launch_bounds__(256) void ea_perm(const float* __restrict__ ea,
                                               const int* __restrict__ eidx,
                                               const int* __restrict__ totE_p,
                                               float* __restrict__ eac) {
    int j = blockIdx.x * 256 + threadIdx.x;
    if (j >= *totE_p) return;
    int e = eidx[j];
    if ((unsigned)e >= NE) e = 0;
    const float* s = ea + (size_t)e * 16;
    float* d = eac + (size_t)j * 16;
#pragma unroll
    for (int k = 0; k < 4; ++k)
        *(f32x4*)(d + k * 4) = *(const f32x4*)(s + k * 4);
}

// ---------------- CSR build: histogram -> scan -> fill ----------------
__global__ __launch_bounds__(256) void hist_dst(const int* __restrict__ ei,
                                                const int* __restrict__ flag,
                                                int* __restrict__ deg) {
    int e = blockIdx.x * 256 + threadIdx.x;
    if (e >= NE) return;
    int f64 = *flag;
    int s = load_idx(ei, e, f64);
    int d = load_idx(ei, (long long)NE + e, f64);
    if ((unsigned)s < NN && (unsigned)d < NN) atomicAdd(&deg[d], 1);
}

__global__ __launch_bounds__(256) void scan_bsum(const int* __restrict__ deg,
                                                 int* __restrict__ bsum) {
    __shared__ int red[256];
    int t = threadIdx.x, base = blockIdx.x * SCHUNK + t * 4;
    int s = 0;
#pragma unroll
    for (int c = 0; c < 4; ++c) { int i = base + c; if (i < NN) s += deg[i]; }
    red[t] = s; __syncthreads();
    for (int o = 128; o > 0; o >>= 1) { if (t < o) red[t] += red[t + o]; __syncthreads(); }
    if (t == 0) bsum[blockIdx.x] = red[0];
}

__global__ void scan_carry(int* __restrict__ bsum, int* __restrict__ rowptr_end) {
    if (threadIdx.x == 0) {
        int run = 0;
        for (int i = 0; i < NSCAN; ++i) { int v = bsum[i]; bsum[i] = run; run += v; }
        *rowptr_end = run;   // rowptr[NN] = totE
    }
}

__global__ __launch_bounds__(256) void scan_final(const int* __restrict__ deg,
                                                  const int* __restrict__ bsum,
                                                  int* __restrict__ rowptr) {
    __shared__ int lds[256];
    int t = threadIdx.x, base = blockIdx.x * SCHUNK + t * 4;
    int v[4], s = 0;
#pragma unroll
    for (int c = 0; c < 4; ++c) { int i = base + c; v[c] = (i < NN) ? deg[i] : 0; s += v[c]; }
    lds[t] = s; __syncthreads();
    for (int o = 1; o < 256; o <<= 1) {
        int x = 0;
        if (t >= o) x = lds[t - o];
        __syncthreads();
        if (t >= o) lds[t] += x;
        __syncthreads();
    }
    int run = lds[t] - s + bsum[blockIdx.x];
#pragma unroll
    for (int c = 0; c < 4; ++c) { int i = base + c; if (i < NN) rowptr[i] = run; run += v[c]; }
}

__global__ __launch_bounds__(256) void fill_csr(const int* __restrict__ ei,
                                                const int* __restrict__ flag,
                                                int* __restrict__ cursor,
                                                int* __restrict__ srcs,
                                                int* __restrict__ eidx) {
    int e = blockIdx.x * 256 + threadIdx.x;
    if (e >= NE) return;
    int f64 = *flag;
    int s = load_idx(ei, e, f64);
    int d = load_idx(ei, (long long)NE + e, f64);
    if ((unsigned)s >= NN || (unsigned)d >= NN) return;
    int pos = atomicAdd(&cursor[d], 1);
    if ((unsigned)pos < NE) { srcs[pos] = s; eidx[pos] = e; }
}

// ---------------- stage 1: edge-parallel message build (packed f32x2 MLP) ----------------
template<int C>
__global__ __launch_bounds__(256)
void msg_build(const unsigned short* __restrict__ xh,
               const float* __restrict__ eac,
               const float* __restrict__ We, const float* __restrict__ be,
               const int* __restrict__ srcs, const int* __restrict__ totE_p,
               unsigned short* __restrict__ M) {
    using XV = typename VecT<C>::T;
    constexpr int D = 64 * C;
    constexpr int C2 = C / 2;
    const int wid  = (blockIdx.x * 256 + threadIdx.x) >> 6;
    const int lane = threadIdx.x & 63;
    const int totE = *totE_p;
    const int col = lane * C;

    f32x2 w2[16][C2], bb2[C2];
#pragma unroll
    for (int k = 0; k < 16; ++k)
#pragma unroll
        for (int c = 0; c < C2; ++c)
            w2[k][c] = *(const f32x2*)(We + k * D + col + 2 * c);
#pragma unroll
    for (int c = 0; c < C2; ++c) bb2[c] = *(const f32x2*)(be + col + 2 * c);

    const int j0 = wid * 4;
    int sv[4];
    XV xv[4];
#pragma unroll
    for (int u = 0; u < 4; ++u) {
        int j = j0 + u;
        sv[u] = (j < totE) ? srcs[j] : -1;
    }
#pragma unroll
    for (int u = 0; u < 4; ++u) {
        if ((unsigned)sv[u] < NN)
            xv[u] = *(const XV*)(xh + (size_t)sv[u] * D + col);
        else
            xv[u] = (XV)0;
    }
#pragma unroll
    for (int u = 0; u < 4; ++u) {
        int j = j0 + u;
        if (j >= totE) continue;
        const float* eap = eac + (size_t)j * 16;
        f32x4 e0 = *(const f32x4*)eap;
        f32x4 e1 = *(const f32x4*)(eap + 4);
        f32x4 e2 = *(const f32x4*)(eap + 8);
        f32x4 e3 = *(const f32x4*)(eap + 12);
        f32x2 m2[C2];
#pragma unroll
        for (int c = 0; c < C2; ++c) {
            f32x2 xx; xx.x = bf2f(xv[u][2 * c]); xx.y = bf2f(xv[u][2 * c + 1]);
            m2[c] = bb2[c] + xx;
        }
#pragma unroll
        for (int k = 0; k < 4; ++k) {
            f32x2 k0; k0.x = e0[k]; k0.y = e0[k];
            f32x2 k1; k1.x = e1[k]; k1.y = e1[k];
            f32x2 k2; k2.x = e2[k]; k2.y = e2[k];
            f32x2 k3; k3.x = e3[k]; k3.y = e3[k];
#pragma unroll
            for (int c = 0; c < C2; ++c) {
                m2[c] += k0 * w2[k][c];
                m2[c] += k1 * w2[4 + k][c];
                m2[c] += k2 * w2[8 + k][c];
                m2[c] += k3 * w2[12 + k][c];
            }
        }
        XV o;
#pragma unroll
        for (int c = 0; c < C2; ++c) {
            o[2 * c]     = f2bf(fmaxf(m2[c].x, 0.f));
            o[2 * c + 1] = f2bf(fmaxf(m2[c].y, 0.f));
        }
        *(XV*)(M + (size_t)j * D + col) = o;
    }
}

// ---------------- stage 2: segment-sum ----------------
template<int C>
__global__ __launch_bounds__(256)
void seg_sum(const unsigned short* __restrict__ M, const int* __restrict__ rowptr,
             const unsigned short* __restrict__ self, unsigned short* __restrict__ outp) {
    using XV = typename VecT<C>::T;
    constexpr int D = 64 * C;
    const int node = (blockIdx.x * 256 + threadIdx.x) >> 6;
    const int lane = threadIdx.x & 63;
    if (node >= NN) return;
    const int col = lane * C;
    int lo = rowptr[node], hi = rowptr[node + 1];
    if (lo > hi || (unsigned)hi > NE) { lo = 0; hi = 0; }

    float a[C];
    XV sv = *(const XV*)(self + (size_t)node * D + col);
#pragma unroll
    for (int c = 0; c < C; ++c) a[c] = bf2f(sv[c]);

    int j = lo;
    for (; j + 1 < hi; j += 2) {
        XV m0 = *(const XV*)(M + (size_t)j * D + col);
        XV m1 = *(const XV*)(M + (size_t)(j + 1) * D + col);
#pragma unroll
        for (int c = 0; c < C; ++c) a[c] += bf2f(m0[c]) + bf2f(m1[c]);
    }
    if (j < hi) {
        XV m0 = *(const XV*)(M + (size_t)j * D + col);
#pragma unroll
        for (int c = 0; c < C; ++c) a[c] += bf2f(m0[c]);
    }
    XV o;
#pragma unroll
    for (int c = 0; c < C; ++c) o[c] = f2bf(a[c]);
    *(XV*)(outp + (size_t)node * D + col) = o;
}

// ------- bf16 MFMA GEMM v4: block 64m x 256n(full), 4 waves each 64x64, BK=64 -------
// C[M,256] = relu(A @ W + bias); A bf16 [M,K], Wt bf16 [n][k].
// LDS pad +4 shorts -> row stride 34 dwords === 2 (mod 32): fragment bank =
// 2*lm + 4*lq -> max 2-way aliasing (free, m136). Staging: 4 threads/row read
// 128 B contiguous -> full cache lines, no overfetch. A read ONCE from HBM
// (single n-block); B (<=128 KB) stays L2-hot across the 3125 m-blocks.
template<int K, typename CT>
__global__ __launch_bounds__(256)
void gemm_bias_relu(const unsigned short* __restrict__ A,
                    const unsigned short* __restrict__ Wt, const float* __restrict__ bias,
                    CT* __restrict__ C) {
    constexpr int LDT = 68;                     // 64 + 4 shorts
    __shared__ unsigned short As[64 * LDT];     //  8.7 KB
    __shared__ unsigned short Bs[256 * LDT];    // 34.8 KB
    const int m0 = blockIdx.x * 64;
    const int tid = threadIdx.x;
    const int wave = tid >> 6;
    const int lane = tid & 63;
    const int lm = lane & 15;
    const int lq = lane >> 4;
    const int nw = wave * 64;                   // wave n-offset

    const int srow = tid >> 2;                  // staging: 4 threads/row
    const int scol = (tid & 3) * 16;            // 16 shorts = 32 B each

    f32x4 acc[4][4] = {};

    for (int k0 = 0; k0 < K; k0 += 64) {
        // ---- stage A: 64 rows x 64 k ----
        {
            const unsigned short* src = A + (size_t)(m0 + srow) * K + k0 + scol;
            unsigned short* dst = As + srow * LDT + scol;
            *(u16x8*)(dst)     = *(const u16x8*)(src);
            *(u16x8*)(dst + 8) = *(const u16x8*)(src + 8);
        }
        // ---- stage B: 256 rows x 64 k (4 rows/thread) ----
#pragma unroll
        for (int rr = 0; rr < 4; ++rr) {
            int r = srow + rr * 64;
            const unsigned short* src = Wt + (size_t)r * K + k0 + scol;
            unsigned short* dst = Bs + r * LDT + scol;
            *(u16x8*)(dst)     = *(const u16x8*)(src);
            *(u16x8*)(dst + 8) = *(const u16x8*)(src + 8);
        }
        __syncthreads();
#pragma unroll
        for (int ks = 0; ks < 2; ++ks) {
            s16x8 af[4], bf[4];
#pragma unroll
            for (int mt = 0; mt < 4; ++mt)
                af[mt] = *(const s16x8*)(As + (mt * 16 + lm) * LDT + ks * 32 + lq * 8);
#pragma unroll
            for (int nt = 0; nt < 4; ++nt)
                bf[nt] = *(const s16x8*)(Bs + (nw + nt * 16 + lm) * LDT + ks * 32 + lq * 8);
#pragma unroll
            for (int mt = 0; mt < 4; ++mt)
#pragma unroll
                for (int nt = 0; nt < 4; ++nt)
                    acc[mt][nt] = __builtin_amdgcn_mfma_f32_16x16x32_bf16(
                        af[mt], bf[nt], acc[mt][nt], 0, 0, 0);
        }
        __syncthreads();
    }

    // epilogue: C/D layout col=lane&15, row=(lane>>4)*4+reg
#pragma unroll
    for (int mt = 0; mt < 4; ++mt) {
        const int row = m0 + mt * 16 + lq * 4;
#pragma unroll
        for (int nt = 0; nt < 4; ++nt) {
            int col = nw + nt * 16 + lm;
            float bv = bias[col];
#pragma unroll
            for (int r = 0; r < 4; ++r) {
                float v = fmaxf(acc[mt][nt][r] + bv, 0.f);
                if constexpr (sizeof(CT) == 2)
                    C[(size_t)(row + r) * 256 + col] = (CT)f2bf(v);
                else
                    C[(size_t)(row + r) * 256 + col] = (CT)v;
            }
        }
    }
}

// ------- mean pool -------
__global__ __launch_bounds__(256)
void pool_mean(const float* __restrict__ h, const int* __restrict__ batch,
               const int* __restrict__ flag, float* __restrict__ out) {
    const int f64 = *flag;
    int g = blockIdx.x;
    int a = 0, b = NN;
    while (a < b) { int m = (a + b) >> 1; if (load_idx(batch, m, f64) < g) a = m + 1; else b = m; }
    int lo = a;
    b = NN;
    while (a < b) { int m = (a + b) >> 1; if (load_idx(batch, m, f64) < g + 1) a = m + 1; else b = m; }
    int hi = a;
    int f = threadIdx.x;
    float s = 0.f;
    for (int n = lo; n < hi; ++n) s += h[(size_t)n * 256 + f];
    float cnt = (float)(hi - lo);
    out[(size_t)g * 256 + f] = s / fmaxf(cnt, 1.f);
}

extern "C" void kernel_launch(void* const* d_in, const int* in_sizes, int n_in,
                              void* d_out, int out_size, void* d_ws, size_t ws_size,
                              hipStream_t stream) {
    const float* x   = (const float*)d_in[0];
    const float* ea  = (const float*)d_in[1];
    const float* We1 = (const float*)d_in[2];
    const float* be1 = (const float*)d_in[3];
    const float* W1a = (const float*)d_in[4];
    const float* b1a = (const float*)d_in[5];
    const float* W1b = (const float*)d_in[6];
    const float* b1b = (const float*)d_in[7];
    const float* We2 = (const float*)d_in[8];
    const float* be2 = (const float*)d_in[9];
    const float* W2a = (const float*)d_in[10];
    const float* b2a = (const float*)d_in[11];
    const float* W2b = (const float*)d_in[12];
    const float* b2b = (const float*)d_in[13];
    const int*   ei  = (const int*)d_in[14];
    const int*   bat = (const int*)d_in[15];
    float* out = (float*)d_out;

    // ---- workspace: EXACT round-2-proven footprint (410,058,756 B) ----
    char* ws = (char*)d_ws;
    const size_t SZH = (size_t)NN * 256 * 2;   // 102,400,000
    unsigned short* A  = (unsigned short*)ws;
    unsigned short* B  = (unsigned short*)(ws + SZH);
    unsigned short* Cr = (unsigned short*)(ws + 2 * SZH);
    char* Dr = ws + 3 * SZH;
    char* q = Dr;
    int* deg    = (int*)q; q += (size_t)NN * 4;
    int* rowptr = (int*)q; q += (size_t)(NN + 1) * 4;
    int* cursor = (int*)q; q += (size_t)NN * 4;
    int* srcs   = (int*)q; q += (size_t)NE * 4;
    int* eidx   = (int*)q; q += (size_t)NE * 4;
    int* bsum   = (int*)q; q += (size_t)NSCAN * 4;
    q = Dr + ((q - Dr + 63) & ~63ll);
    float*          eac = (float*)q; q += (size_t)NE * 16 * 4;   // 25.6 MB
    unsigned short* xh  = (unsigned short*)q;                    // 51.2 MB
    char* p = ws + 4 * SZH;
    unsigned short* Wt1a = (unsigned short*)p; p += 128 * 256 * 2;
    unsigned short* Wt1b = (unsigned short*)p; p += 256 * 256 * 2;
    unsigned short* Wt2a = (unsigned short*)p; p += 256 * 256 * 2;
    unsigned short* Wt2b = (unsigned short*)p; p += 256 * 256 * 2;
    int* flag = (int*)p;

    detect_i64<<<1, 64, 0, stream>>>(ei, flag);
    wt_conv<<<(128 * 256 + 255) / 256, 256, 0, stream>>>(W1a, Wt1a, 128, 256);
    wt_conv<<<(256 * 256 + 255) / 256, 256, 0, stream>>>(W1b, Wt1b, 256, 256);
    wt_conv<<<(256 * 256 + 255) / 256, 256, 0, stream>>>(W2a, Wt2a, 256, 256);
    wt_conv<<<(256 * 256 + 255) / 256, 256, 0, stream>>>(W2b, Wt2b, 256, 256);

    // ---- CSR build (once; shared by both layers) ----
    hipMemsetAsync(deg, 0, (size_t)NN * 4, stream);
    hist_dst<<<(NE + 255) / 256, 256, 0, stream>>>(ei, flag, deg);
    scan_bsum<<<NSCAN, 256, 0, stream>>>(deg, bsum);
    scan_carry<<<1, 64, 0, stream>>>(bsum, rowptr + NN);
    scan_final<<<NSCAN, 256, 0, stream>>>(deg, bsum, rowptr);
    copy_int<<<(NN + 255) / 256, 256, 0, stream>>>(rowptr, cursor, NN);
    fill_csr<<<(NE + 255) / 256, 256, 0, stream>>>(ei, flag, cursor, srcs, eidx);
    ea_perm<<<(NE + 255) / 256, 256, 0, stream>>>(ea, eidx, rowptr + NN, eac);
    x2bf<<<(NN * 128 / 4 + 255) / 256, 256, 0, stream>>>(x, xh);

    const int GM_BLK = NE / 16;   // 25000: 4 waves x 4 slots per block
    const int GS_BLK = NN / 4;    // 50000: wave per node
    const int GG_BLK = NN / 64;   // 3125: GEMM m-blocks (full N per block)

    // ---- layer 1 (D=128) ----
    msg_build<2><<<GM_BLK, 256, 0, stream>>>(xh, eac, We1, be1, srcs, rowptr + NN, A);   // M1 -> A
    seg_sum<2><<<GS_BLK, 256, 0, stream>>>(A, rowptr, xh, B);                            // hin1 -> B
    gemm_bias_relu<128, unsigned short><<<GG_BLK, 256, 0, stream>>>(B, Wt1a, b1a, Cr);   // h1 -> C
    gemm_bias_relu<256, unsigned short><<<GG_BLK, 256, 0, stream>>>(Cr, Wt1b, b1b, A);   // h1o -> A

    // ---- layer 2 (D=256, single full-width pass) ----
    msg_build<4><<<GM_BLK, 256, 0, stream>>>(A, eac, We2, be2, srcs, rowptr + NN, B);    // M2 -> B∪C
    seg_sum<4><<<GS_BLK, 256, 0, stream>>>(B, rowptr, A, A);                             // hin2 in-place A
    gemm_bias_relu<256, unsigned short><<<GG_BLK, 256, 0, stream>>>(A, Wt2a, b2a, B);    // h2a -> B
    gemm_bias_relu<256, float><<<GG_BLK, 256, 0, stream>>>(B, Wt2b, b2b, (float*)Cr);    // h2b f32 -> C∪D

    // ---- mean pool ----
    pool_mean<<<NG, 256, 0, stream>>>((const float*)Cr, bat, flag, out);
}